// Round 4
// baseline (637.103 us; speedup 1.0000x reference)
//
#include <hip/hip_runtime.h>
#include <math.h>

typedef __attribute__((ext_vector_type(4))) float f32x4;
typedef __attribute__((ext_vector_type(8))) short short8;
typedef unsigned int u32;

#define B_DIM 8192
#define N_FEAT 2048
#define K_ROWS 4096
#define INV_T 2.0f
#define EPSF 1e-12f

// gram tiling: 96x96 tiles over a 43x43 grid (upper triangle incl. diagonal)
#define GT 96
#define GGRID 43            // ceil(4096/96)
#define NTILES 946          // 43*44/2

// workspace layout (bytes)
#define FT_OFF    0ull
#define NORM2_OFF 67108864ull                 // fT = 4096*8192*2 bytes
#define INV_OFF   (NORM2_OFF + 16384)
#define SUMSQ_OFF (INV_OFF + 16384)
#define RSUM_OFF  (SUMSQ_OFF + 16384)
#define PDOT_OFF  (RSUM_OFF + 16384)
#define ENT_OFF   (PDOT_OFF + 8192)           // 256 doubles of entropy partials
#define WS_END    (ENT_OFF + 2048)

__device__ __forceinline__ unsigned short f2bf(float x) {
  u32 u = __float_as_uint(x);
  u32 r = (u + 0x7fffu + ((u >> 16) & 1u)) >> 16;  // RNE, inputs are finite
  return (unsigned short)r;
}

__device__ __forceinline__ void gload16(const void* g, void* l) {
  __builtin_amdgcn_global_load_lds((const __attribute__((address_space(1))) u32*)g,
                                   (__attribute__((address_space(3))) u32*)l, 16, 0, 0);
}

// ---------------------------------------------------------------------------
// K1: fused prep. Per block: one 64(b) x 64(k) tile of f1 AND f2.
//  - entropy partial sum (256-slot double array, avoids same-address f64 chain)
//  - norm2[k] (fp32 atomics), posdot[k] (fp32 atomics)
//  - transpose to fT (bf16, unnormalized), sumsq[row] = sum of bf16^2 (fp32)
// ---------------------------------------------------------------------------
__global__ __launch_bounds__(256) void prep_kernel(
    const float* __restrict__ f1, const float* __restrict__ f2,
    unsigned short* __restrict__ fT, float* __restrict__ norm2,
    float* __restrict__ posdot, float* __restrict__ sumsq,
    double* __restrict__ entpart) {
  __shared__ float T1[64][65];
  __shared__ float T2[64][65];
  __shared__ float entp[4];
  const int bt = blockIdx.x, kt = blockIdx.y;
  const int b0 = bt * 64, k0 = kt * 64;
  const int t = threadIdx.x;
  const int lane = t & 63, wave = t >> 6;
  const int kq = t & 15;   // float4 column group within tile
  const int br = t >> 4;   // base row 0..15

  float n1[4] = {0.f, 0.f, 0.f, 0.f};
  float n2[4] = {0.f, 0.f, 0.f, 0.f};
  float pd[4] = {0.f, 0.f, 0.f, 0.f};
  float ent = 0.f;
#pragma unroll
  for (int rr = 0; rr < 4; ++rr) {
    const int b = br + rr * 16;
    const f32x4 v1 = *(const f32x4*)&f1[(size_t)(b0 + b) * N_FEAT + k0 + kq * 4];
    const f32x4 v2 = *(const f32x4*)&f2[(size_t)(b0 + b) * N_FEAT + k0 + kq * 4];
#pragma unroll
    for (int c = 0; c < 4; ++c) {
      const float x = v1[c], y = v2[c];
      n1[c] += x * x; n2[c] += y * y; pd[c] += x * y;
      ent += -x * __logf(x + EPSF) - (1.f - x) * __logf(1.f - x + EPSF);
      ent += -y * __logf(y + EPSF) - (1.f - y) * __logf(1.f - y + EPSF);
      T1[b][kq * 4 + c] = x;
      T2[b][kq * 4 + c] = y;
    }
  }
  // reduce across the 4 row-groups within the wave (lanes ^16, ^32 share kq)
#pragma unroll
  for (int c = 0; c < 4; ++c) {
    n1[c] += __shfl_xor(n1[c], 16); n1[c] += __shfl_xor(n1[c], 32);
    n2[c] += __shfl_xor(n2[c], 16); n2[c] += __shfl_xor(n2[c], 32);
    pd[c] += __shfl_xor(pd[c], 16); pd[c] += __shfl_xor(pd[c], 32);
  }
  if (lane < 16) {
#pragma unroll
    for (int c = 0; c < 4; ++c) {
      atomicAdd(&norm2[k0 + kq * 4 + c], n1[c]);
      atomicAdd(&norm2[N_FEAT + k0 + kq * 4 + c], n2[c]);
      atomicAdd(&posdot[k0 + kq * 4 + c], pd[c]);
    }
  }
#pragma unroll
  for (int off = 1; off < 64; off <<= 1) ent += __shfl_xor(ent, off);
  if (lane == 0) entp[wave] = ent;
  __syncthreads();
  if (t == 0)
    atomicAdd(&entpart[(blockIdx.y * gridDim.x + blockIdx.x) & 255],
              (double)(entp[0] + entp[1] + entp[2] + entp[3]));

  // phase W: write transposed bf16 rows; 4 threads per feature row, 16 b each
  const int kl = t >> 2;
  const int b8 = (t & 3) * 16;
  {
    short8 o0, o1; float sq = 0.f;
#pragma unroll
    for (int j = 0; j < 8; ++j) {
      const unsigned short us = f2bf(T1[b8 + j][kl]);
      const float xb = __uint_as_float((u32)us << 16);
      sq += xb * xb; o0[j] = (short)us;
    }
#pragma unroll
    for (int j = 8; j < 16; ++j) {
      const unsigned short us = f2bf(T1[b8 + j][kl]);
      const float xb = __uint_as_float((u32)us << 16);
      sq += xb * xb; o1[j - 8] = (short)us;
    }
    const size_t gi = (size_t)(k0 + kl);
    *(short8*)&fT[gi * B_DIM + b0 + b8] = o0;
    *(short8*)&fT[gi * B_DIM + b0 + b8 + 8] = o1;
    sq += __shfl_xor(sq, 1); sq += __shfl_xor(sq, 2);
    if ((t & 3) == 0) atomicAdd(&sumsq[gi], sq);
  }
  {
    short8 o0, o1; float sq = 0.f;
#pragma unroll
    for (int j = 0; j < 8; ++j) {
      const unsigned short us = f2bf(T2[b8 + j][kl]);
      const float xb = __uint_as_float((u32)us << 16);
      sq += xb * xb; o0[j] = (short)us;
    }
#pragma unroll
    for (int j = 8; j < 16; ++j) {
      const unsigned short us = f2bf(T2[b8 + j][kl]);
      const float xb = __uint_as_float((u32)us << 16);
      sq += xb * xb; o1[j - 8] = (short)us;
    }
    const size_t gi = (size_t)(N_FEAT + k0 + kl);
    *(short8*)&fT[gi * B_DIM + b0 + b8] = o0;
    *(short8*)&fT[gi * B_DIM + b0 + b8 + 8] = o1;
    sq += __shfl_xor(sq, 1); sq += __shfl_xor(sq, 2);
    if ((t & 3) == 0) atomicAdd(&sumsq[gi], sq);
  }
}

// K1b: inv[i] = 1 / max(||row i||, eps)
__global__ void inv_kernel(const float* __restrict__ norm2, float* __restrict__ inv) {
  const int i = blockIdx.x * 256 + threadIdx.x;
  if (i < K_ROWS) inv[i] = 1.f / fmaxf(sqrtf(norm2[i]), EPSF);
}

// ---------------------------------------------------------------------------
// K2: symmetric Gram tiles (ti <= tj), 96x96 tile, BK=64, 4 waves (2x2, each
// 48x48 = 3x3 fragments), mfma_f32_16x16x32_bf16.
// 946 blocks, __launch_bounds__(256,4) pins VGPR<=128 -> 4 blocks/CU
// resident; static makespan 4 vs 3.70 avg = ~8% tail (vs ~45% at 528x128^2).
// Ragged edge (43*96=4128>4096): staging rows clamped per-lane on the GLOBAL
// address (LDS dest stays linear), invalid entries zeroed post-exp, atomics
// guarded. Epilogue: exp(dot*inv_i*inv_j/T), row+col sums -> rowsum atomics.
// ---------------------------------------------------------------------------
__global__ __launch_bounds__(256, 4) void gram_kernel(
    const unsigned short* __restrict__ fT, const float* __restrict__ inv,
    float* __restrict__ rowsum) {
  __shared__ __align__(16) unsigned short Al[GT * 64];
  __shared__ __align__(16) unsigned short Bl[GT * 64];
  // bijective XCD swizzle (m204): nwg=946, q=118, r=2
  const int orig = blockIdx.x;
  const int xcd = orig & 7;
  const int bid = (xcd < 2 ? xcd * 119 : 238 + (xcd - 2) * 118) + (orig >> 3);
  // triangular decode: bid -> (ti <= tj)
  int r = (int)((sqrtf(8.f * (float)bid + 1.f) - 1.f) * 0.5f);
  while ((r + 1) * (r + 2) / 2 <= bid) ++r;
  while (r * (r + 1) / 2 > bid) --r;
  const int tj = r, ti = bid - r * (r + 1) / 2;

  const int t = threadIdx.x, lane = t & 63, wave = t >> 6;
  const int wr = wave >> 1, wc = wave & 1;
  const int Rb = wr * 48, Cb = wc * 48;
  const int rowl = lane & 15, lhi = lane >> 4;
  const int srow8 = wave * 8 + (lane >> 3);  // staging row within 32-row group
  const int scol = (lane & 7) * 8;           // staging col (elements)
  const int tb = ti * GT, tjb = tj * GT;

  // per-lane staging source pointers, row clamped to 4095 (ragged edge)
  const unsigned short* pa[3];
  const unsigned short* pb[3];
#pragma unroll
  for (int it = 0; it < 3; ++it) {
    int ra = tb + it * 32 + srow8;  ra = ra < K_ROWS - 1 ? ra : K_ROWS - 1;
    int rb2 = tjb + it * 32 + srow8; rb2 = rb2 < K_ROWS - 1 ? rb2 : K_ROWS - 1;
    pa[it] = fT + (size_t)ra * B_DIM + scol;
    pb[it] = fT + (size_t)rb2 * B_DIM + scol;
  }

  f32x4 acc[3][3];
  const f32x4 zero = {0.f, 0.f, 0.f, 0.f};
#pragma unroll
  for (int m = 0; m < 3; ++m)
#pragma unroll
    for (int n = 0; n < 3; ++n) acc[m][n] = zero;

  for (int kt = 0; kt < B_DIM / 64; ++kt) {
    const size_t ko = (size_t)kt * 64;
#pragma unroll
    for (int it = 0; it < 3; ++it) {
      gload16(pa[it] + ko, &Al[(it * 32 + wave * 8) * 64]);
      gload16(pb[it] + ko, &Bl[(it * 32 + wave * 8) * 64]);
    }
    asm volatile("s_waitcnt vmcnt(0)" ::: "memory");
    __syncthreads();
#pragma unroll
    for (int kk = 0; kk < 64; kk += 32) {
      short8 af[3], bfv[3];
      const int kc = kk + lhi * 8;
#pragma unroll
      for (int m = 0; m < 3; ++m)
        af[m] = *(const short8*)&Al[(Rb + m * 16 + rowl) * 64 + kc];
#pragma unroll
      for (int n = 0; n < 3; ++n)
        bfv[n] = *(const short8*)&Bl[(Cb + n * 16 + rowl) * 64 + kc];
#pragma unroll
      for (int m = 0; m < 3; ++m)
#pragma unroll
        for (int n = 0; n < 3; ++n)
          acc[m][n] = __builtin_amdgcn_mfma_f32_16x16x32_bf16(af[m], bfv[n], acc[m][n], 0, 0, 0);
    }
    __syncthreads();
  }

  // epilogue: scale, exp, zero invalid (ragged) entries, row + col sums
  float invj[3];
  bool cval[3];
#pragma unroll
  for (int n = 0; n < 3; ++n) {
    const int cg = tjb + Cb + n * 16 + rowl;
    cval[n] = cg < K_ROWS;
    invj[n] = inv[cg < K_ROWS ? cg : K_ROWS - 1];
  }
#pragma unroll
  for (int m = 0; m < 3; ++m) {
#pragma unroll
    for (int rg = 0; rg < 4; ++rg) {
      const int rgl = tb + Rb + m * 16 + lhi * 4 + rg;
      const bool rv = rgl < K_ROWS;
      const float invi = inv[rv ? rgl : K_ROWS - 1];
#pragma unroll
      for (int n = 0; n < 3; ++n) {
        const float e = __expf(acc[m][n][rg] * invi * invj[n] * INV_T);
        acc[m][n][rg] = (rv && cval[n]) ? e : 0.f;
      }
    }
  }
  // row-side sums (rows of ti)
#pragma unroll
  for (int m = 0; m < 3; ++m) {
#pragma unroll
    for (int rg = 0; rg < 4; ++rg) {
      float s = acc[m][0][rg] + acc[m][1][rg] + acc[m][2][rg];
      s += __shfl_xor(s, 1); s += __shfl_xor(s, 2);
      s += __shfl_xor(s, 4); s += __shfl_xor(s, 8);
      if (rowl == 0) {
        const int rgl = tb + Rb + m * 16 + lhi * 4 + rg;
        if (rgl < K_ROWS) atomicAdd(&rowsum[rgl], s);
      }
    }
  }
  // col-side sums (rows of tj) for off-diagonal tiles
  if (ti != tj) {
#pragma unroll
    for (int n = 0; n < 3; ++n) {
      float s = 0.f;
#pragma unroll
      for (int m = 0; m < 3; ++m)
#pragma unroll
        for (int rg = 0; rg < 4; ++rg) s += acc[m][n][rg];
      s += __shfl_xor(s, 16); s += __shfl_xor(s, 32);
      if (lhi == 0) {
        const int cg = tjb + Cb + n * 16 + rowl;
        if (cg < K_ROWS) atomicAdd(&rowsum[cg], s);
      }
    }
  }
}

// ---------------------------------------------------------------------------
// K3: lse_i = log(rowsum_i - exp(diag_i)), pos_i exact fp32; final scalar.
// ---------------------------------------------------------------------------
__global__ __launch_bounds__(256) void final_kernel(
    const float* __restrict__ rowsum, const float* __restrict__ sumsq,
    const float* __restrict__ inv, const float* __restrict__ posdot,
    const double* __restrict__ entpart, float* __restrict__ out) {
  __shared__ double red[4];
  __shared__ double rede[4];
  const int t = threadIdx.x, lane = t & 63, wave = t >> 6;
  double ssum = 0.0;
  for (int i = t; i < K_ROWS; i += 256) {
    const float invi = inv[i];
    const float diag = __expf(sumsq[i] * invi * invi * INV_T);
    const float lse = __logf(rowsum[i] - diag);
    const int ip = (i < N_FEAT) ? i : i - N_FEAT;
    const int io = (i < N_FEAT) ? i + N_FEAT : i - N_FEAT;
    const float pos = posdot[ip] * invi * inv[io] * INV_T;
    ssum += (double)(lse - pos);
  }
  double esum = entpart[t];
#pragma unroll
  for (int off = 1; off < 64; off <<= 1) {
    ssum += __shfl_xor(ssum, off);
    esum += __shfl_xor(esum, off);
  }
  if (lane == 0) { red[wave] = ssum; rede[wave] = esum; }
  __syncthreads();
  if (t == 0) {
    const double ce = (red[0] + red[1] + red[2] + red[3]) / (double)K_ROWS;
    const double etot = rede[0] + rede[1] + rede[2] + rede[3];
    const double nel = etot / ((double)K_ROWS * (double)B_DIM * 0.6931471805599453);
    out[0] = (float)(ce - nel);
  }
}

extern "C" void kernel_launch(void* const* d_in, const int* in_sizes, int n_in,
                              void* d_out, int out_size, void* d_ws, size_t ws_size,
                              hipStream_t stream) {
  const float* f1 = (const float*)d_in[0];
  const float* f2 = (const float*)d_in[1];
  char* ws = (char*)d_ws;
  unsigned short* fT = (unsigned short*)(ws + FT_OFF);
  float* norm2 = (float*)(ws + NORM2_OFF);
  float* inv = (float*)(ws + INV_OFF);
  float* sumsq = (float*)(ws + SUMSQ_OFF);
  float* rowsum = (float*)(ws + RSUM_OFF);
  float* posdot = (float*)(ws + PDOT_OFF);
  double* entpart = (double*)(ws + ENT_OFF);

  // zero all accumulators (ws is poisoned 0xAA before every call)
  hipMemsetAsync(ws + NORM2_OFF, 0, (size_t)(WS_END - NORM2_OFF), stream);

  dim3 g1(B_DIM / 64, N_FEAT / 64);
  prep_kernel<<<g1, 256, 0, stream>>>(f1, f2, fT, norm2, posdot, sumsq, entpart);
  inv_kernel<<<K_ROWS / 256, 256, 0, stream>>>(norm2, inv);
  gram_kernel<<<NTILES, 256, 0, stream>>>(fT, inv, rowsum);
  final_kernel<<<1, 256, 0, stream>>>(rowsum, sumsq, inv, posdot, entpart, (float*)d_out);
}

// Round 5
// 392.304 us; speedup vs baseline: 1.6240x; 1.6240x over previous
//
#include <hip/hip_runtime.h>
#include <math.h>

typedef __attribute__((ext_vector_type(4))) float f32x4;
typedef __attribute__((ext_vector_type(8))) short short8;
typedef unsigned int u32;

#define B_DIM 8192
#define N_FEAT 2048
#define K_ROWS 4096
#define INV_T 2.0f
#define EPSF 1e-12f

// gram tiling: 96x96 tiles over a 43x43 grid (upper triangle incl. diagonal)
#define GT 96
#define GGRID 43            // ceil(4096/96)
#define NTILES 946          // 43*44/2

// workspace layout (bytes)
#define FT_OFF    0ull
#define NORM2_OFF 67108864ull                 // fT = 4096*8192*2 bytes
#define INV_OFF   (NORM2_OFF + 16384)
#define SUMSQ_OFF (INV_OFF + 16384)           // unused (diag zeroed in gram now)
#define RSUM_OFF  (SUMSQ_OFF + 16384)
#define PDOT_OFF  (RSUM_OFF + 16384)
#define ENT_OFF   (PDOT_OFF + 8192)           // 256 doubles of entropy partials
#define WS_END    (ENT_OFF + 2048)

__device__ __forceinline__ unsigned short f2bf(float x) {
  u32 u = __float_as_uint(x);
  u32 r = (u + 0x7fffu + ((u >> 16) & 1u)) >> 16;  // RNE, inputs are finite
  return (unsigned short)r;
}

__device__ __forceinline__ void gload16(const void* g, void* l) {
  __builtin_amdgcn_global_load_lds((const __attribute__((address_space(1))) u32*)g,
                                   (__attribute__((address_space(3))) u32*)l, 16, 0, 0);
}

// ---------------------------------------------------------------------------
// K_B: pure streaming stats. Thread-per-column, coalesced 1KB/wave row loads,
// no LDS, no __syncthreads, no transcendental-free phases to serialize.
//  norm2[k] = sum_b f[k,b]^2 (fp32 atomics), posdot[k] = sum_b f1*f2,
//  entropy in BITS (log2): neloss == mean(ent_bits), no ln2 factor needed.
// ---------------------------------------------------------------------------
__global__ __launch_bounds__(256) void stats_kernel(
    const float* __restrict__ f1, const float* __restrict__ f2,
    float* __restrict__ norm2, float* __restrict__ posdot,
    double* __restrict__ entpart) {
  const int col = blockIdx.x * 256 + threadIdx.x;
  const size_t base = (size_t)blockIdx.y * 64 * N_FEAT + col;
  const float* p1 = f1 + base;
  const float* p2 = f2 + base;
  float n1 = 0.f, n2 = 0.f, pd = 0.f, e0 = 0.f, e1 = 0.f;
#pragma unroll 8
  for (int r = 0; r < 64; ++r) {
    const float x = p1[(size_t)r * N_FEAT];
    const float y = p2[(size_t)r * N_FEAT];
    n1 += x * x; n2 += y * y; pd += x * y;
    e0 -= x * __log2f(x + EPSF) + (1.f - x) * __log2f(1.f - x + EPSF);
    e1 -= y * __log2f(y + EPSF) + (1.f - y) * __log2f(1.f - y + EPSF);
  }
  atomicAdd(&norm2[col], n1);
  atomicAdd(&norm2[N_FEAT + col], n2);
  atomicAdd(&posdot[col], pd);
  float ent = e0 + e1;
#pragma unroll
  for (int off = 1; off < 64; off <<= 1) ent += __shfl_xor(ent, off);
  if ((threadIdx.x & 63) == 0)
    atomicAdd(&entpart[(blockIdx.y * 8 + blockIdx.x + (threadIdx.x >> 6) * 64) & 255],
              (double)ent);
}

// ---------------------------------------------------------------------------
// K_A: transpose-only. 64(b) x 64(k) tile of f1 AND f2 -> bf16 fT rows.
// No atomics, no transcendentals: load -> LDS -> convert -> short8 stores.
// ---------------------------------------------------------------------------
__global__ __launch_bounds__(256) void transpose_kernel(
    const float* __restrict__ f1, const float* __restrict__ f2,
    unsigned short* __restrict__ fT) {
  __shared__ float T1[64][65];
  __shared__ float T2[64][65];
  const int b0 = blockIdx.x * 64, k0 = blockIdx.y * 64;
  const int t = threadIdx.x;
  const int kq = t & 15, br = t >> 4;
#pragma unroll
  for (int rr = 0; rr < 4; ++rr) {
    const int b = br + rr * 16;
    const f32x4 v1 = *(const f32x4*)&f1[(size_t)(b0 + b) * N_FEAT + k0 + kq * 4];
    const f32x4 v2 = *(const f32x4*)&f2[(size_t)(b0 + b) * N_FEAT + k0 + kq * 4];
#pragma unroll
    for (int c = 0; c < 4; ++c) { T1[b][kq * 4 + c] = v1[c]; T2[b][kq * 4 + c] = v2[c]; }
  }
  __syncthreads();
  const int kl = t >> 2;
  const int b8 = (t & 3) * 16;
  short8 o0, o1;
#pragma unroll
  for (int j = 0; j < 8; ++j)  o0[j] = (short)f2bf(T1[b8 + j][kl]);
#pragma unroll
  for (int j = 8; j < 16; ++j) o1[j - 8] = (short)f2bf(T1[b8 + j][kl]);
  size_t gi = (size_t)(k0 + kl);
  *(short8*)&fT[gi * B_DIM + b0 + b8] = o0;
  *(short8*)&fT[gi * B_DIM + b0 + b8 + 8] = o1;
#pragma unroll
  for (int j = 0; j < 8; ++j)  o0[j] = (short)f2bf(T2[b8 + j][kl]);
#pragma unroll
  for (int j = 8; j < 16; ++j) o1[j - 8] = (short)f2bf(T2[b8 + j][kl]);
  gi = (size_t)(N_FEAT + k0 + kl);
  *(short8*)&fT[gi * B_DIM + b0 + b8] = o0;
  *(short8*)&fT[gi * B_DIM + b0 + b8 + 8] = o1;
}

// K1b: inv[i] = 1 / max(||row i||, eps)
__global__ void inv_kernel(const float* __restrict__ norm2, float* __restrict__ inv) {
  const int i = blockIdx.x * 256 + threadIdx.x;
  if (i < K_ROWS) inv[i] = 1.f / fmaxf(sqrtf(norm2[i]), EPSF);
}

// ---------------------------------------------------------------------------
// K2: symmetric Gram tiles (ti <= tj), 96x96 tile, BK=64, 4 waves (2x2, each
// 48x48 = 3x3 fragments), mfma_f32_16x16x32_bf16.
// Diagonal tiles ZERO their row==col element post-exp -> rowsum directly
// excludes the main diagonal (no sumsq array / final exp needed).
// Ragged edge (43*96=4128>4096): staging rows clamped per-lane on the GLOBAL
// address (LDS dest stays linear), invalid entries zeroed post-exp, atomics
// guarded. Epilogue: exp(dot*inv_i*inv_j/T), row+col sums -> rowsum atomics.
// ---------------------------------------------------------------------------
__global__ __launch_bounds__(256, 4) void gram_kernel(
    const unsigned short* __restrict__ fT, const float* __restrict__ inv,
    float* __restrict__ rowsum) {
  __shared__ __align__(16) unsigned short Al[GT * 64];
  __shared__ __align__(16) unsigned short Bl[GT * 64];
  // bijective XCD swizzle (m204): nwg=946, q=118, r=2
  const int orig = blockIdx.x;
  const int xcd = orig & 7;
  const int bid = (xcd < 2 ? xcd * 119 : 238 + (xcd - 2) * 118) + (orig >> 3);
  // triangular decode: bid -> (ti <= tj)
  int r = (int)((sqrtf(8.f * (float)bid + 1.f) - 1.f) * 0.5f);
  while ((r + 1) * (r + 2) / 2 <= bid) ++r;
  while (r * (r + 1) / 2 > bid) --r;
  const int tj = r, ti = bid - r * (r + 1) / 2;

  const int t = threadIdx.x, lane = t & 63, wave = t >> 6;
  const int wr = wave >> 1, wc = wave & 1;
  const int Rb = wr * 48, Cb = wc * 48;
  const int rowl = lane & 15, lhi = lane >> 4;
  const int srow8 = wave * 8 + (lane >> 3);  // staging row within 32-row group
  const int scol = (lane & 7) * 8;           // staging col (elements)
  const int tb = ti * GT, tjb = tj * GT;
  const bool diagT = (ti == tj);

  // per-lane staging source pointers, row clamped to 4095 (ragged edge)
  const unsigned short* pa[3];
  const unsigned short* pb[3];
#pragma unroll
  for (int it = 0; it < 3; ++it) {
    int ra = tb + it * 32 + srow8;  ra = ra < K_ROWS - 1 ? ra : K_ROWS - 1;
    int rb2 = tjb + it * 32 + srow8; rb2 = rb2 < K_ROWS - 1 ? rb2 : K_ROWS - 1;
    pa[it] = fT + (size_t)ra * B_DIM + scol;
    pb[it] = fT + (size_t)rb2 * B_DIM + scol;
  }

  f32x4 acc[3][3];
  const f32x4 zero = {0.f, 0.f, 0.f, 0.f};
#pragma unroll
  for (int m = 0; m < 3; ++m)
#pragma unroll
    for (int n = 0; n < 3; ++n) acc[m][n] = zero;

  for (int kt = 0; kt < B_DIM / 64; ++kt) {
    const size_t ko = (size_t)kt * 64;
#pragma unroll
    for (int it = 0; it < 3; ++it) {
      gload16(pa[it] + ko, &Al[(it * 32 + wave * 8) * 64]);
      gload16(pb[it] + ko, &Bl[(it * 32 + wave * 8) * 64]);
    }
    asm volatile("s_waitcnt vmcnt(0)" ::: "memory");
    __syncthreads();
#pragma unroll
    for (int kk = 0; kk < 64; kk += 32) {
      short8 af[3], bfv[3];
      const int kc = kk + lhi * 8;
#pragma unroll
      for (int m = 0; m < 3; ++m)
        af[m] = *(const short8*)&Al[(Rb + m * 16 + rowl) * 64 + kc];
#pragma unroll
      for (int n = 0; n < 3; ++n)
        bfv[n] = *(const short8*)&Bl[(Cb + n * 16 + rowl) * 64 + kc];
#pragma unroll
      for (int m = 0; m < 3; ++m)
#pragma unroll
        for (int n = 0; n < 3; ++n)
          acc[m][n] = __builtin_amdgcn_mfma_f32_16x16x32_bf16(af[m], bfv[n], acc[m][n], 0, 0, 0);
    }
    __syncthreads();
  }

  // epilogue: scale, exp, zero invalid (ragged) + main-diagonal entries,
  // then row + col sums
  float invj[3];
  bool cval[3];
#pragma unroll
  for (int n = 0; n < 3; ++n) {
    const int cg = tjb + Cb + n * 16 + rowl;
    cval[n] = cg < K_ROWS;
    invj[n] = inv[cg < K_ROWS ? cg : K_ROWS - 1];
  }
#pragma unroll
  for (int m = 0; m < 3; ++m) {
#pragma unroll
    for (int rg = 0; rg < 4; ++rg) {
      const int rloc = Rb + m * 16 + lhi * 4 + rg;  // row within tile
      const int rgl = tb + rloc;
      const bool rv = rgl < K_ROWS;
      const float invi = inv[rv ? rgl : K_ROWS - 1];
#pragma unroll
      for (int n = 0; n < 3; ++n) {
        const int cloc = Cb + n * 16 + rowl;        // col within tile
        const float e = __expf(acc[m][n][rg] * invi * invj[n] * INV_T);
        const bool keep = rv && cval[n] && !(diagT && rloc == cloc);
        acc[m][n][rg] = keep ? e : 0.f;
      }
    }
  }
  // row-side sums (rows of ti)
#pragma unroll
  for (int m = 0; m < 3; ++m) {
#pragma unroll
    for (int rg = 0; rg < 4; ++rg) {
      float s = acc[m][0][rg] + acc[m][1][rg] + acc[m][2][rg];
      s += __shfl_xor(s, 1); s += __shfl_xor(s, 2);
      s += __shfl_xor(s, 4); s += __shfl_xor(s, 8);
      if (rowl == 0) {
        const int rgl = tb + Rb + m * 16 + lhi * 4 + rg;
        if (rgl < K_ROWS) atomicAdd(&rowsum[rgl], s);
      }
    }
  }
  // col-side sums (rows of tj) for off-diagonal tiles
  if (!diagT) {
#pragma unroll
    for (int n = 0; n < 3; ++n) {
      float s = 0.f;
#pragma unroll
      for (int m = 0; m < 3; ++m)
#pragma unroll
        for (int rg = 0; rg < 4; ++rg) s += acc[m][n][rg];
      s += __shfl_xor(s, 16); s += __shfl_xor(s, 32);
      if (lhi == 0) {
        const int cg = tjb + Cb + n * 16 + rowl;
        if (cg < K_ROWS) atomicAdd(&rowsum[cg], s);
      }
    }
  }
}

// ---------------------------------------------------------------------------
// K3: lse_i = log(rowsum_i)  (diag excluded in gram), pos_i exact fp32;
// neloss = mean of entropy-in-bits. Final scalar.
// ---------------------------------------------------------------------------
__global__ __launch_bounds__(256) void final_kernel(
    const float* __restrict__ rowsum,
    const float* __restrict__ inv, const float* __restrict__ posdot,
    const double* __restrict__ entpart, float* __restrict__ out) {
  __shared__ double red[4];
  __shared__ double rede[4];
  const int t = threadIdx.x, lane = t & 63, wave = t >> 6;
  double ssum = 0.0;
  for (int i = t; i < K_ROWS; i += 256) {
    const float invi = inv[i];
    const float lse = __logf(rowsum[i]);
    const int ip = (i < N_FEAT) ? i : i - N_FEAT;
    const int io = (i < N_FEAT) ? i + N_FEAT : i - N_FEAT;
    const float pos = posdot[ip] * invi * inv[io] * INV_T;
    ssum += (double)(lse - pos);
  }
  double esum = entpart[t];
#pragma unroll
  for (int off = 1; off < 64; off <<= 1) {
    ssum += __shfl_xor(ssum, off);
    esum += __shfl_xor(esum, off);
  }
  if (lane == 0) { red[wave] = ssum; rede[wave] = esum; }
  __syncthreads();
  if (t == 0) {
    const double ce = (red[0] + red[1] + red[2] + red[3]) / (double)K_ROWS;
    const double etot = rede[0] + rede[1] + rede[2] + rede[3];
    const double nel = etot / ((double)K_ROWS * (double)B_DIM);  // already bits
    out[0] = (float)(ce - nel);
  }
}

extern "C" void kernel_launch(void* const* d_in, const int* in_sizes, int n_in,
                              void* d_out, int out_size, void* d_ws, size_t ws_size,
                              hipStream_t stream) {
  const float* f1 = (const float*)d_in[0];
  const float* f2 = (const float*)d_in[1];
  char* ws = (char*)d_ws;
  unsigned short* fT = (unsigned short*)(ws + FT_OFF);
  float* norm2 = (float*)(ws + NORM2_OFF);
  float* inv = (float*)(ws + INV_OFF);
  float* rowsum = (float*)(ws + RSUM_OFF);
  float* posdot = (float*)(ws + PDOT_OFF);
  double* entpart = (double*)(ws + ENT_OFF);

  // zero all accumulators (ws is poisoned 0xAA before every call)
  hipMemsetAsync(ws + NORM2_OFF, 0, (size_t)(WS_END - NORM2_OFF), stream);

  stats_kernel<<<dim3(N_FEAT / 256, 128), 256, 0, stream>>>(f1, f2, norm2, posdot, entpart);
  inv_kernel<<<K_ROWS / 256, 256, 0, stream>>>(norm2, inv);
  transpose_kernel<<<dim3(B_DIM / 64, N_FEAT / 64), 256, 0, stream>>>(f1, f2, fT);
  gram_kernel<<<NTILES, 256, 0, stream>>>(fT, inv, rowsum);
  final_kernel<<<1, 256, 0, stream>>>(rowsum, inv, posdot, entpart, (float*)d_out);
}